// Round 17
// baseline (532.862 us; speedup 1.0000x reference)
//
#include <hip/hip_runtime.h>
#include <math.h>
#include <stdint.h>

typedef _Float16 f16;
typedef f16 f16x8 __attribute__((ext_vector_type(8)));
typedef f16 f16x4 __attribute__((ext_vector_type(4)));
typedef f16 f16x2 __attribute__((ext_vector_type(2)));
typedef float f32x4 __attribute__((ext_vector_type(4)));

#define N_ITERS 7
#define HF 10      // GRU hidden size
#define NIN 9      // node inputs
#define EF 11      // edge features / message size
#define GIN (EF + NIN)

#define S1 40      // f16 row stride for W1 (K=32 padded)
#define S2 104     // f16 row stride for W2/W3/W4
#define G  2       // 16-edge groups per wave (32 edges/wave)
#define EPB 128    // edges per block (4 waves x 32)
#define MSTR 12    // msg row stride in f32 (11 + 1 pad, 48B)
#define RSTR 40    // f16 stride of LDS edge record (80B; 64B payload + pad)

#define LPN 8      // lanes per node in gru kernel

union FragU { f16x8 v; uint32_t u[4]; uint2 p2[2]; uint4 q4; };

// sigma: column permutation so that layer-L accumulators feed layer-L+1 B
// fragments in-register.  Slot k = 32*kb + 8*q + j holds original activation
// index 32*kb + 16*(j>>2) + 4*q + (j&3)  (tile t = 2*kb + (j>>2), reg r = j&3).
__device__ __forceinline__ int sigmap(int k) {
    return 32 * (k >> 5) + 16 * ((k >> 2) & 1) + 4 * ((k >> 3) & 3) + (k & 3);
}

// ---------------- weight preconversion + edge counting (one dispatch) ------
__global__ __launch_bounds__(256) void convert_and_count(
    const float* __restrict__ W1, const float* __restrict__ W2,
    const float* __restrict__ W3, const float* __restrict__ W4,
    f16* __restrict__ wf,
    const int* __restrict__ dst, int* __restrict__ cnt, int E)
{
    const int tid = blockIdx.x * 256 + threadIdx.x;
    const int nt = gridDim.x * 256;

    if (tid < E) atomicAdd(&cnt[dst[tid]], 1);

    f16* wf1 = wf;
    f16* wf2 = wf1 + 96 * S1;
    f16* wf3 = wf2 + 96 * S2;
    f16* wf4 = wf3 + 96 * S2;
    for (int i = tid; i < 96 * S1; i += nt) {
        int m = i / S1, k = i % S1;
        wf1[i] = (k < 31) ? (f16)W1[m * 31 + k] : (f16)0.f;
    }
    for (int i = tid; i < 96 * S2; i += nt) {
        int m = i / S2, k = i % S2;
        wf2[i] = (k < 96) ? (f16)W2[m * 96 + sigmap(k)] : (f16)0.f;
        wf3[i] = (k < 96) ? (f16)W3[m * 96 + sigmap(k)] : (f16)0.f;
    }
    for (int i = tid; i < 16 * S2; i += nt) {
        int m = i / S2, k = i % S2;
        wf4[i] = (m < 11 && k < 96) ? (f16)W4[m * 96 + sigmap(k)] : (f16)0.f;
    }
}

__global__ __launch_bounds__(1024) void scan_counts(
    const int* __restrict__ cnt, int* __restrict__ row_ptr,
    int* __restrict__ nxt, int N, int E)
{
    __shared__ int sums[1024];
    const int tid = threadIdx.x;
    const int C = (N + 1023) >> 10;
    const int base = tid * C;
    int local = 0;
    for (int i = 0; i < C; ++i) {
        int idx = base + i;
        if (idx < N) local += cnt[idx];
    }
    sums[tid] = local;
    __syncthreads();
    for (int off = 1; off < 1024; off <<= 1) {
        int v = (tid >= off) ? sums[tid - off] : 0;
        __syncthreads();
        sums[tid] += v;
        __syncthreads();
    }
    int run = sums[tid] - local;   // exclusive prefix of this chunk
    for (int i = 0; i < C; ++i) {
        int idx = base + i;
        if (idx < N) {
            row_ptr[idx] = run;
            nxt[idx] = run;
            run += cnt[idx];
        }
    }
    if (tid == 0) row_ptr[N] = E;
}

// scatter + pack fused: place edge e at its dst-sorted slot and emit the
// converted f16 edge attrs directly.
__global__ __launch_bounds__(256) void scatter_pack(
    const int* __restrict__ src, const int* __restrict__ dst,
    const float* __restrict__ ea, int* __restrict__ nxt,
    int* __restrict__ srcs, int* __restrict__ dsts,
    f16* __restrict__ eaA, f16* __restrict__ eaB, int E)
{
    int e = blockIdx.x * 256 + threadIdx.x;
    if (e >= E) return;
    const int d = dst[e];
    const int pos = atomicAdd(&nxt[d], 1);
    srcs[pos] = src[e];
    dsts[pos] = d;
    const float* r = ea + (size_t)e * EF;
    f16x4 a;
#pragma unroll
    for (int j = 0; j < 4; ++j) a[j] = (f16)r[j];
    *(f16x4*)(eaA + (size_t)pos * 4) = a;
    f16x8 b;
#pragma unroll
    for (int j = 0; j < 7; ++j) b[j] = (f16)r[4 + j];
    b[7] = (f16)0.f;
    *(f16x8*)(eaB + (size_t)pos * 8) = b;
}

// relu + pack, 4 VALU inst (ROUND-14 VERSION, measured best): 2x
// v_cvt_f16_f32 (RTN — bit-identical numerics) + pack + v_pk_max_f16.
// Round 16's 2-inst RTZ pkrtz variant measured SLOWER (446.0 vs 440.5) —
// VALU count is no longer the binding constraint; do not re-try.
__device__ __forceinline__ uint32_t pack_relu2(float x, float y) {
    union { f16x2 h; uint32_t u; } r;
    r.h[0] = (f16)x;
    r.h[1] = (f16)y;
    const f16x2 z = { (f16)0.f, (f16)0.f };
    r.h = __builtin_elementwise_max(r.h, z);   // v_pk_max_f16
    return r.u;
}

// mid layer, t-outer / g-inner: only 3 weight fragments (12 VGPR) live at a
// time — prevents per-group weight rematerialization (round-8/9, verified).
#define MID_LAYER(WPTR, BPTR, IN, OUT)                                        \
    {                                                                         \
        _Pragma("unroll")                                                     \
        for (int t = 0; t < 6; ++t) {                                         \
            const f16x8 a0 = *(const f16x8*)(WPTR + (t * 16 + n) * S2 + 0 * 32 + 8 * q); \
            const f16x8 a1 = *(const f16x8*)(WPTR + (t * 16 + n) * S2 + 1 * 32 + 8 * q); \
            const f16x8 a2 = *(const f16x8*)(WPTR + (t * 16 + n) * S2 + 2 * 32 + 8 * q); \
            const f32x4 bias = *(const f32x4*)(BPTR + t * 16 + 4 * q);        \
            _Pragma("unroll")                                                 \
            for (int g = 0; g < G; ++g) {                                     \
                f32x4 c = bias;                                               \
                c = __builtin_amdgcn_mfma_f32_16x16x32_f16(a0, IN[g][0].v, c, 0, 0, 0); \
                c = __builtin_amdgcn_mfma_f32_16x16x32_f16(a1, IN[g][1].v, c, 0, 0, 0); \
                c = __builtin_amdgcn_mfma_f32_16x16x32_f16(a2, IN[g][2].v, c, 0, 0, 0); \
                OUT[g][t >> 1].u[2 * (t & 1) + 0] = pack_relu2(c[0], c[1]);   \
                OUT[g][t >> 1].u[2 * (t & 1) + 1] = pack_relu2(c[2], c[3]);   \
            }                                                                 \
        }                                                                     \
    }

// ---------------- edge MLP via MFMA, G=2 (occupancy via SMALLER waves) -----
// Round-17 change: G 4->2.  Per-wave live state drops (bfrA+bfrB 96->48
// VGPR) and LDS halves (10 KB/block), so MORE blocks/CU fit — occupancy
// rises by shrinking per-wave state, the inverse of the spilling attempts
// (rounds 7/10/12: growing live state past ~115 VGPR always spilled).
// Weight reloads double (27 f16x8/wave, L1/L2-hot — cheap).
// Phase 1: threads 0..127 each gather ONE edge record into LDS; barrier
// (rows now cross waves; barrier measured neutral in round 13).
// Phase 2: one ds_read_b128 per group -> layer-1 B fragment; layers 2/3/4
// fully in-register via sigma-permuted weights, t-outer.
// s_setprio(1) around compute (T5, round 14: part of the -17us).
// launch_bounds(256,2): KNOWN-GOOD.  Do not fuse; do not raise the bound.
__global__ __launch_bounds__(256, 2) void edge_mlp_mfma(
    const f16* __restrict__ h16, const f16* __restrict__ wf,
    const float* __restrict__ b1, const float* __restrict__ b2,
    const float* __restrict__ b3, const float* __restrict__ b4,
    const int* __restrict__ srcs, const int* __restrict__ dsts,
    const f16* __restrict__ eaA, const f16* __restrict__ eaB,
    float* __restrict__ msg, int E)
{
    const f16* wf1 = wf;
    const f16* wf2 = wf1 + 96 * S1;
    const f16* wf3 = wf2 + 96 * S2;
    const f16* wf4 = wf3 + 96 * S2;

    __shared__ f16 rec[EPB][RSTR];   // 10,240 B

    const int wave = threadIdx.x >> 6;
    const int lane = threadIdx.x & 63;
    const int n = lane & 15;       // edge-in-group (B col / C col)
    const int q = lane >> 4;       // quad

    const int i0 = blockIdx.x * EPB + wave * (G * 16);

    // ---------------- phase 1: threads 0..127 gather one record each -------
    {
        const int tid = threadIdx.x;
        if (tid < EPB) {
            const int i = blockIdx.x * EPB + tid;
            const int ii = (i < E) ? i : 0;
            const int s = srcs[ii];
            const int d = dsts[ii];
            const uint4* h16q = (const uint4*)h16;
            const uint32_t* h16u = (const uint32_t*)h16;
            uint4 hs0 = h16q[(size_t)s * 2];                  // h_s[0..7]
            uint32_t hs1 = h16u[(size_t)s * 8 + 4];           // h_s[8,9]
            uint4 hd0 = h16q[(size_t)d * 2];                  // h_d[0..7]
            uint32_t hd1 = h16u[(size_t)d * 8 + 4];           // h_d[8,9]
            uint2 ea0 = ((const uint2*)eaA)[ii];              // ea[0..3]
            uint4 ea1 = ((const uint4*)eaB)[ii];              // ea[4..10],0
            uint4 w1 = { hs1, hd0.x, hd0.y, hd0.z };
            uint4 w2 = { hd0.w, hd1, ea0.x, ea0.y };
            uint4* rp = (uint4*)&rec[tid][0];                 // 80B stride
            rp[0] = hs0;
            rp[1] = w1;
            rp[2] = w2;
            rp[3] = ea1;
        }
    }
    __syncthreads();

    __builtin_amdgcn_s_setprio(1);

    // double-buffered per-group activation fragments (registers, 48 VGPR)
    FragU bfrA[G][3];
    FragU bfrB[G][3];

    // ---------------- layer 1: [31] -> [96], relu, t-outer ----------------
    {
        FragU bf[G];
#pragma unroll
        for (int g = 0; g < G; ++g)
            bf[g].v = *(const f16x8*)&rec[wave * (G * 16) + g * 16 + n][q * 8];
#pragma unroll
        for (int t = 0; t < 6; ++t) {
            const f16x8 a = *(const f16x8*)(wf1 + (t * 16 + n) * S1 + 8 * q);
            const f32x4 bias = *(const f32x4*)(b1 + t * 16 + 4 * q);
#pragma unroll
            for (int g = 0; g < G; ++g) {
                f32x4 c = __builtin_amdgcn_mfma_f32_16x16x32_f16(a, bf[g].v, bias, 0, 0, 0);
                bfrA[g][t >> 1].u[2 * (t & 1) + 0] = pack_relu2(c[0], c[1]);
                bfrA[g][t >> 1].u[2 * (t & 1) + 1] = pack_relu2(c[2], c[3]);
            }
        }
    }

    // ---------------- layers 2,3: [96] -> [96], relu, in-register ---------
    MID_LAYER(wf2, b2, bfrA, bfrB)
    MID_LAYER(wf3, b3, bfrB, bfrA)

    // ---------------- layer 4: [96] -> [11(+pad)], coalesced msg write ------
    {
        const f16x8 a0 = *(const f16x8*)(wf4 + n * S2 + 0 * 32 + 8 * q);
        const f16x8 a1 = *(const f16x8*)(wf4 + n * S2 + 1 * 32 + 8 * q);
        const f16x8 a2 = *(const f16x8*)(wf4 + n * S2 + 2 * 32 + 8 * q);
        float bias[4];
#pragma unroll
        for (int r = 0; r < 4; ++r) {
            const int m = 4 * q + r;
            bias[r] = (m < 11) ? b4[m] : 0.0f;
        }
#pragma unroll
        for (int g = 0; g < G; ++g) {
            f32x4 c = { bias[0], bias[1], bias[2], bias[3] };
            c = __builtin_amdgcn_mfma_f32_16x16x32_f16(a0, bfrA[g][0].v, c, 0, 0, 0);
            c = __builtin_amdgcn_mfma_f32_16x16x32_f16(a1, bfrA[g][1].v, c, 0, 0, 0);
            c = __builtin_amdgcn_mfma_f32_16x16x32_f16(a2, bfrA[g][2].v, c, 0, 0, 0);
            const int ig = i0 + g * 16 + n;
            if (q < 3 && ig < E)   // rows m=0..11; m=11 is exact 0 (zero-padded W4/b4)
                *(f32x4*)(msg + (size_t)ig * MSTR + 4 * q) = c;
        }
    }

    __builtin_amdgcn_s_setprio(0);
}

// ---------------- GRU + CSR aggregation + logits, 8 lanes per node --------
// Lane sub accumulates rows r0+sub, r0+sub+8, ...; 3-step shfl_xor butterfly
// leaves x[] in all lanes; all lanes compute the GRU redundantly (scalar
// accumulators only — no runtime-indexed arrays, rule #20); lane 0 stores.
__global__ __launch_bounds__(256) void gru_node_kernel(
    const float* __restrict__ node_inputs,
    float* __restrict__ h, f16* __restrict__ h16,
    const int* __restrict__ row_ptr, const float* __restrict__ msg,
    const float* __restrict__ wih, const float* __restrict__ whh,
    const float* __restrict__ bih, const float* __restrict__ bhh,
    const float* __restrict__ fw, const float* __restrict__ fb,
    float* __restrict__ out_t, int N)
{
    const int T = blockIdx.x * blockDim.x + threadIdx.x;
    const int n = T / LPN;
    const int sub = T & (LPN - 1);
    if (n >= N) return;

    float x[GIN];
#pragma unroll
    for (int k = 0; k < EF; ++k) x[k] = 0.0f;
    const int r0 = row_ptr[n], r1 = row_ptr[n + 1];
    for (int r = r0 + sub; r < r1; r += LPN) {
        const f32x4* mp = (const f32x4*)(msg + (size_t)r * MSTR);
        f32x4 a = mp[0], b = mp[1], c = mp[2];
        x[0] += a[0]; x[1] += a[1]; x[2] += a[2]; x[3] += a[3];
        x[4] += b[0]; x[5] += b[1]; x[6] += b[2]; x[7] += b[3];
        x[8] += c[0]; x[9] += c[1]; x[10] += c[2];
    }
    // butterfly reduce across the 8-lane group (stays within the wave)
#pragma unroll
    for (int off = 1; off < LPN; off <<= 1) {
#pragma unroll
        for (int k = 0; k < EF; ++k)
            x[k] += __shfl_xor(x[k], off);
    }
#pragma unroll
    for (int k = 0; k < NIN; ++k) x[EF + k] = node_inputs[(size_t)n * NIN + k];

    float hv[HF];
#pragma unroll
    for (int k = 0; k < HF; ++k) hv[k] = h[(size_t)n * HF + k];

    float hn[HF];
#pragma unroll
    for (int k = 0; k < HF; ++k) {
        float gir = bih[k];
        float giz = bih[HF + k];
        float gin = bih[2 * HF + k];
        float ghr = bhh[k];
        float ghz = bhh[HF + k];
        float ghn = bhh[2 * HF + k];
#pragma unroll
        for (int kk = 0; kk < GIN; ++kk) {
            gir = fmaf(x[kk], wih[(size_t)k * GIN + kk], gir);
            giz = fmaf(x[kk], wih[(size_t)(HF + k) * GIN + kk], giz);
            gin = fmaf(x[kk], wih[(size_t)(2 * HF + k) * GIN + kk], gin);
        }
#pragma unroll
        for (int kk = 0; kk < HF; ++kk) {
            ghr = fmaf(hv[kk], whh[(size_t)k * HF + kk], ghr);
            ghz = fmaf(hv[kk], whh[(size_t)(HF + k) * HF + kk], ghz);
            ghn = fmaf(hv[kk], whh[(size_t)(2 * HF + k) * HF + kk], ghn);
        }
        const float r2 = 1.0f / (1.0f + __expf(-(gir + ghr)));
        const float z  = 1.0f / (1.0f + __expf(-(giz + ghz)));
        const float nn = tanhf(gin + r2 * ghn);
        hn[k] = (1.0f - z) * nn + z * hv[k];
    }

    if (sub == 0) {
#pragma unroll
        for (int k = 0; k < HF; ++k) h[(size_t)n * HF + k] = hn[k];
        union { f16 hh[8]; uint4 q; } p4;
#pragma unroll
        for (int k = 0; k < 8; ++k) p4.hh[k] = (f16)hn[k];
        *(uint4*)(h16 + (size_t)n * 16) = p4.q;
        union { f16 hh[2]; uint32_t u; } p1;
        p1.hh[0] = (f16)hn[8]; p1.hh[1] = (f16)hn[9];
        *(uint32_t*)(h16 + (size_t)n * 16 + 8) = p1.u;

        float l0 = fb[0], l1 = fb[1];
#pragma unroll
        for (int k = 0; k < HF; ++k) {
            l0 = fmaf(hn[k], fw[k], l0);
            l1 = fmaf(hn[k], fw[HF + k], l1);
        }
        float2 lo = { l0, l1 };
        *(float2*)(out_t + (size_t)n * 2) = lo;
    }
}

extern "C" void kernel_launch(void* const* d_in, const int* in_sizes, int n_in,
                              void* d_out, int out_size, void* d_ws, size_t ws_size,
                              hipStream_t stream) {
    const float* node_inputs = (const float*)d_in[0];
    const float* edge_attr   = (const float*)d_in[1];
    const float* W1 = (const float*)d_in[2];
    const float* b1 = (const float*)d_in[3];
    const float* W2 = (const float*)d_in[4];
    const float* b2 = (const float*)d_in[5];
    const float* W3 = (const float*)d_in[6];
    const float* b3 = (const float*)d_in[7];
    const float* W4 = (const float*)d_in[8];
    const float* b4 = (const float*)d_in[9];
    const float* gru_wih = (const float*)d_in[10];
    const float* gru_whh = (const float*)d_in[11];
    const float* gru_bih = (const float*)d_in[12];
    const float* gru_bhh = (const float*)d_in[13];
    const float* fin_w   = (const float*)d_in[14];
    const float* fin_b   = (const float*)d_in[15];
    const int* src_ids = (const int*)d_in[16];
    const int* dst_ids = (const int*)d_in[17];

    const int N = in_sizes[0] / NIN;   // 20000
    const int E = in_sizes[1] / EF;    // 320000

    // ---- workspace carve-up (256B-aligned chunks) ----
    char* base = (char*)d_ws;
    size_t off = 0;
    auto alloc = [&](size_t bytes) -> char* {
        char* p = base + off;
        off += (bytes + 255) & ~(size_t)255;
        return p;
    };
    float* msg    = (float*)alloc((size_t)E * MSTR * 4);  // 15.4 MB
    f16*   eaB    = (f16*)  alloc((size_t)E * 8 * 2);
    f16*   eaA    = (f16*)  alloc((size_t)E * 4 * 2);
    // h16, hbuf, cnt kept CONTIGUOUS so one memset clears all three
    f16*   h16    = (f16*)  alloc((size_t)N * 16 * 2);
    float* hbuf   = (float*)alloc((size_t)N * HF * 4);
    int*   cnt    = (int*)  alloc((size_t)N * 4);
    f16*   wf     = (f16*)  alloc(52000 * 2);
    int*   row_ptr= (int*)  alloc((size_t)(N + 1) * 4);
    int*   nxt    = (int*)  alloc((size_t)N * 4);
    int*   srcs   = (int*)  alloc((size_t)E * 4);
    int*   dsts   = (int*)  alloc((size_t)E * 4);

    const int eb = (E + 255) / 256;
    const int ebe = (E + EPB - 1) / EPB;   // edge blocks (128 edges each)
    const int nb = (N * LPN + 255) / 256;

    // ---- per-launch setup (d_ws is re-poisoned before every call) ----
    const size_t zspan = (size_t)((char*)cnt + (size_t)N * 4 - (char*)h16);
    hipMemsetAsync(h16, 0, zspan, stream);   // h16 + hbuf + cnt in one shot
    convert_and_count<<<eb, 256, 0, stream>>>(W1, W2, W3, W4, wf,
                                              dst_ids, cnt, E);
    scan_counts<<<1, 1024, 0, stream>>>(cnt, row_ptr, nxt, N, E);
    scatter_pack<<<eb, 256, 0, stream>>>(src_ids, dst_ids, edge_attr, nxt,
                                         srcs, dsts, eaA, eaB, E);

    float* out = (float*)d_out;
    for (int t = 0; t < N_ITERS; ++t) {
        edge_mlp_mfma<<<ebe, 256, 0, stream>>>(
            h16, wf, b1, b2, b3, b4, srcs, dsts, eaA, eaB, msg, E);
        gru_node_kernel<<<nb, 256, 0, stream>>>(
            node_inputs, hbuf, h16, row_ptr, msg,
            gru_wih, gru_whh, gru_bih, gru_bhh,
            fin_w, fin_b, out + (size_t)t * N * 2, N);
    }
}

// Round 18
// 435.693 us; speedup vs baseline: 1.2230x; 1.2230x over previous
//
#include <hip/hip_runtime.h>
#include <math.h>
#include <stdint.h>

typedef _Float16 f16;
typedef f16 f16x8 __attribute__((ext_vector_type(8)));
typedef f16 f16x4 __attribute__((ext_vector_type(4)));
typedef f16 f16x2 __attribute__((ext_vector_type(2)));
typedef float f32x4 __attribute__((ext_vector_type(4)));

#define N_ITERS 7
#define HF 10      // GRU hidden size
#define NIN 9      // node inputs
#define EF 11      // edge features / message size
#define GIN (EF + NIN)

#define S1 40      // f16 row stride for W1 (K=32 padded)
#define S2 104     // f16 row stride for W2/W3/W4
#define G  4       // 16-edge groups per wave (ROUND-14 OPTIMUM; G=2 was +92us)
#define MSTR 12    // msg row stride in f32 (11 + 1 pad, 48B)
#define RSTR 40    // f16 stride of LDS edge record (80B; 64B payload + pad)

#define LPN 8      // lanes per node in gru kernel

union FragU { f16x8 v; uint32_t u[4]; uint2 p2[2]; uint4 q4; };

// sigma: column permutation so that layer-L accumulators feed layer-L+1 B
// fragments in-register.  Slot k = 32*kb + 8*q + j holds original activation
// index 32*kb + 16*(j>>2) + 4*q + (j&3)  (tile t = 2*kb + (j>>2), reg r = j&3).
__device__ __forceinline__ int sigmap(int k) {
    return 32 * (k >> 5) + 16 * ((k >> 2) & 1) + 4 * ((k >> 3) & 3) + (k & 3);
}

// ---------------- weight preconversion + edge counting (one dispatch) ------
__global__ __launch_bounds__(256) void convert_and_count(
    const float* __restrict__ W1, const float* __restrict__ W2,
    const float* __restrict__ W3, const float* __restrict__ W4,
    f16* __restrict__ wf,
    const int* __restrict__ dst, int* __restrict__ cnt, int E)
{
    const int tid = blockIdx.x * 256 + threadIdx.x;
    const int nt = gridDim.x * 256;

    if (tid < E) atomicAdd(&cnt[dst[tid]], 1);

    f16* wf1 = wf;
    f16* wf2 = wf1 + 96 * S1;
    f16* wf3 = wf2 + 96 * S2;
    f16* wf4 = wf3 + 96 * S2;
    for (int i = tid; i < 96 * S1; i += nt) {
        int m = i / S1, k = i % S1;
        wf1[i] = (k < 31) ? (f16)W1[m * 31 + k] : (f16)0.f;
    }
    for (int i = tid; i < 96 * S2; i += nt) {
        int m = i / S2, k = i % S2;
        wf2[i] = (k < 96) ? (f16)W2[m * 96 + sigmap(k)] : (f16)0.f;
        wf3[i] = (k < 96) ? (f16)W3[m * 96 + sigmap(k)] : (f16)0.f;
    }
    for (int i = tid; i < 16 * S2; i += nt) {
        int m = i / S2, k = i % S2;
        wf4[i] = (m < 11 && k < 96) ? (f16)W4[m * 96 + sigmap(k)] : (f16)0.f;
    }
}

__global__ __launch_bounds__(1024) void scan_counts(
    const int* __restrict__ cnt, int* __restrict__ row_ptr,
    int* __restrict__ nxt, int N, int E)
{
    __shared__ int sums[1024];
    const int tid = threadIdx.x;
    const int C = (N + 1023) >> 10;
    const int base = tid * C;
    int local = 0;
    for (int i = 0; i < C; ++i) {
        int idx = base + i;
        if (idx < N) local += cnt[idx];
    }
    sums[tid] = local;
    __syncthreads();
    for (int off = 1; off < 1024; off <<= 1) {
        int v = (tid >= off) ? sums[tid - off] : 0;
        __syncthreads();
        sums[tid] += v;
        __syncthreads();
    }
    int run = sums[tid] - local;   // exclusive prefix of this chunk
    for (int i = 0; i < C; ++i) {
        int idx = base + i;
        if (idx < N) {
            row_ptr[idx] = run;
            nxt[idx] = run;
            run += cnt[idx];
        }
    }
    if (tid == 0) row_ptr[N] = E;
}

// scatter + pack fused: place edge e at its dst-sorted slot and emit the
// converted f16 edge attrs + packed (src,dst) pair directly.
__global__ __launch_bounds__(256) void scatter_pack(
    const int* __restrict__ src, const int* __restrict__ dst,
    const float* __restrict__ ea, int* __restrict__ nxt,
    int2* __restrict__ sd,
    f16* __restrict__ eaA, f16* __restrict__ eaB, int E)
{
    int e = blockIdx.x * 256 + threadIdx.x;
    if (e >= E) return;
    const int d = dst[e];
    const int pos = atomicAdd(&nxt[d], 1);
    int2 p = { src[e], d };
    sd[pos] = p;
    const float* r = ea + (size_t)e * EF;
    f16x4 a;
#pragma unroll
    for (int j = 0; j < 4; ++j) a[j] = (f16)r[j];
    *(f16x4*)(eaA + (size_t)pos * 4) = a;
    f16x8 b;
#pragma unroll
    for (int j = 0; j < 7; ++j) b[j] = (f16)r[4 + j];
    b[7] = (f16)0.f;
    *(f16x8*)(eaB + (size_t)pos * 8) = b;
}

// relu + pack, 4 VALU inst (ROUND-14 VERSION, measured best): 2x
// v_cvt_f16_f32 (RTN — bit-identical numerics) + pack + v_pk_max_f16.
// Round 16's 2-inst RTZ pkrtz variant measured SLOWER (446.0 vs 440.5) —
// VALU count is no longer the binding constraint; do not re-try.
__device__ __forceinline__ uint32_t pack_relu2(float x, float y) {
    union { f16x2 h; uint32_t u; } r;
    r.h[0] = (f16)x;
    r.h[1] = (f16)y;
    const f16x2 z = { (f16)0.f, (f16)0.f };
    r.h = __builtin_elementwise_max(r.h, z);   // v_pk_max_f16
    return r.u;
}

// mid layer, t-outer / g-inner: only 3 weight fragments (12 VGPR) live at a
// time — prevents per-group weight rematerialization (round-8/9, verified).
#define MID_LAYER(WPTR, BPTR, IN, OUT)                                        \
    {                                                                         \
        _Pragma("unroll")                                                     \
        for (int t = 0; t < 6; ++t) {                                         \
            const f16x8 a0 = *(const f16x8*)(WPTR + (t * 16 + n) * S2 + 0 * 32 + 8 * q); \
            const f16x8 a1 = *(const f16x8*)(WPTR + (t * 16 + n) * S2 + 1 * 32 + 8 * q); \
            const f16x8 a2 = *(const f16x8*)(WPTR + (t * 16 + n) * S2 + 2 * 32 + 8 * q); \
            const f32x4 bias = *(const f32x4*)(BPTR + t * 16 + 4 * q);        \
            _Pragma("unroll")                                                 \
            for (int g = 0; g < G; ++g) {                                     \
                f32x4 c = bias;                                               \
                c = __builtin_amdgcn_mfma_f32_16x16x32_f16(a0, IN[g][0].v, c, 0, 0, 0); \
                c = __builtin_amdgcn_mfma_f32_16x16x32_f16(a1, IN[g][1].v, c, 0, 0, 0); \
                c = __builtin_amdgcn_mfma_f32_16x16x32_f16(a2, IN[g][2].v, c, 0, 0, 0); \
                OUT[g][t >> 1].u[2 * (t & 1) + 0] = pack_relu2(c[0], c[1]);   \
                OUT[g][t >> 1].u[2 * (t & 1) + 1] = pack_relu2(c[2], c[3]);   \
            }                                                                 \
        }                                                                     \
    }

// ---------------- edge MLP via MFMA (ROUND-14 OPTIMUM CONFIG) --------------
// Phase 1: each thread gathers ONE edge's B-column record into LDS
//          ([h_s(10)|h_d(10)|ea(11)|0] = 32 f16, stride 80B -> 2-way banks).
//          (src,dst) now one coalesced int2 load: gather chain 6 -> 5 loads.
// Phase 2: one ds_read_b128 per group gives the layer-1 B fragment; layers
//          2/3/4 run fully in-register via the sigma-permuted weights,
//          t-outer so weights load once per layer per wave.
// NO __syncthreads between gather and compute (wave-local RAW; DS ops of a
// wave execute in order — round-13 verified).
// s_setprio(1) around compute (T5; round 14: part of the -17us).
// launch_bounds(256,2): KNOWN-GOOD (88 VGPR, no spill).
// CONVERGENCE LEDGER — do not re-try: (256,4) spills (r7); GRU fusion spills
// (r10); gather pipelining spills (r12); barrier removal neutral (r13);
// 2-inst RTZ pack slower (r16); G=2 much slower (r17).
__global__ __launch_bounds__(256, 2) void edge_mlp_mfma(
    const f16* __restrict__ h16, const f16* __restrict__ wf,
    const float* __restrict__ b1, const float* __restrict__ b2,
    const float* __restrict__ b3, const float* __restrict__ b4,
    const int2* __restrict__ sd,
    const f16* __restrict__ eaA, const f16* __restrict__ eaB,
    float* __restrict__ msg, int E)
{
    const f16* wf1 = wf;
    const f16* wf2 = wf1 + 96 * S1;
    const f16* wf3 = wf2 + 96 * S2;
    const f16* wf4 = wf3 + 96 * S2;

    __shared__ f16 rec[256][RSTR];   // 20 KB

    const int wave = threadIdx.x >> 6;
    const int lane = threadIdx.x & 63;
    const int n = lane & 15;       // edge-in-group (B col / C col)
    const int q = lane >> 4;       // quad

    const int i0 = blockIdx.x * 256 + wave * (G * 16);

    // ---------------- phase 1: gather one edge record per thread ----------
    {
        const int tid = threadIdx.x;
        const int i = blockIdx.x * 256 + tid;
        const int ii = (i < E) ? i : 0;
        const int2 p = sd[ii];
        const int s = p.x;
        const int d = p.y;
        const uint4* h16q = (const uint4*)h16;
        const uint32_t* h16u = (const uint32_t*)h16;
        uint4 hs0 = h16q[(size_t)s * 2];                  // h_s[0..7]
        uint32_t hs1 = h16u[(size_t)s * 8 + 4];           // h_s[8,9]
        uint4 hd0 = h16q[(size_t)d * 2];                  // h_d[0..7]
        uint32_t hd1 = h16u[(size_t)d * 8 + 4];           // h_d[8,9]
        uint2 ea0 = ((const uint2*)eaA)[ii];              // ea[0..3]
        uint4 ea1 = ((const uint4*)eaB)[ii];              // ea[4..10],0
        uint4 w1 = { hs1, hd0.x, hd0.y, hd0.z };
        uint4 w2 = { hd0.w, hd1, ea0.x, ea0.y };
        uint4* rp = (uint4*)&rec[tid][0];                 // 80B stride, 16B aligned
        rp[0] = hs0;
        rp[1] = w1;
        rp[2] = w2;
        rp[3] = ea1;
    }
    // wave-local RAW only: pin compiler ordering, no block barrier needed.
    asm volatile("" ::: "memory");

    __builtin_amdgcn_s_setprio(1);

    // double-buffered per-group activation fragments (registers)
    FragU bfrA[G][3];
    FragU bfrB[G][3];

    // ---------------- layer 1: [31] -> [96], relu, t-outer ----------------
    {
        FragU bf[G];
#pragma unroll
        for (int g = 0; g < G; ++g)
            bf[g].v = *(const f16x8*)&rec[wave * 64 + g * 16 + n][q * 8];
#pragma unroll
        for (int t = 0; t < 6; ++t) {
            const f16x8 a = *(const f16x8*)(wf1 + (t * 16 + n) * S1 + 8 * q);
            const f32x4 bias = *(const f32x4*)(b1 + t * 16 + 4 * q);
#pragma unroll
            for (int g = 0; g < G; ++g) {
                f32x4 c = __builtin_amdgcn_mfma_f32_16x16x32_f16(a, bf[g].v, bias, 0, 0, 0);
                bfrA[g][t >> 1].u[2 * (t & 1) + 0] = pack_relu2(c[0], c[1]);
                bfrA[g][t >> 1].u[2 * (t & 1) + 1] = pack_relu2(c[2], c[3]);
            }
        }
    }

    // ---------------- layers 2,3: [96] -> [96], relu, in-register ---------
    MID_LAYER(wf2, b2, bfrA, bfrB)
    MID_LAYER(wf3, b3, bfrB, bfrA)

    // ---------------- layer 4: [96] -> [11(+pad)], coalesced msg write ------
    {
        const f16x8 a0 = *(const f16x8*)(wf4 + n * S2 + 0 * 32 + 8 * q);
        const f16x8 a1 = *(const f16x8*)(wf4 + n * S2 + 1 * 32 + 8 * q);
        const f16x8 a2 = *(const f16x8*)(wf4 + n * S2 + 2 * 32 + 8 * q);
        float bias[4];
#pragma unroll
        for (int r = 0; r < 4; ++r) {
            const int m = 4 * q + r;
            bias[r] = (m < 11) ? b4[m] : 0.0f;
        }
#pragma unroll
        for (int g = 0; g < G; ++g) {
            f32x4 c = { bias[0], bias[1], bias[2], bias[3] };
            c = __builtin_amdgcn_mfma_f32_16x16x32_f16(a0, bfrA[g][0].v, c, 0, 0, 0);
            c = __builtin_amdgcn_mfma_f32_16x16x32_f16(a1, bfrA[g][1].v, c, 0, 0, 0);
            c = __builtin_amdgcn_mfma_f32_16x16x32_f16(a2, bfrA[g][2].v, c, 0, 0, 0);
            const int ig = i0 + g * 16 + n;
            if (q < 3 && ig < E)   // rows m=0..11; m=11 is exact 0 (zero-padded W4/b4)
                *(f32x4*)(msg + (size_t)ig * MSTR + 4 * q) = c;
        }
    }

    __builtin_amdgcn_s_setprio(0);
}

// ---------------- GRU + CSR aggregation + logits, 8 lanes per node --------
// Lane sub accumulates rows r0+sub, r0+sub+8, ...; 3-step shfl_xor butterfly
// leaves x[] in all lanes; all lanes compute the GRU redundantly (scalar
// accumulators only — no runtime-indexed arrays, rule #20); lane 0 stores.
__global__ __launch_bounds__(256) void gru_node_kernel(
    const float* __restrict__ node_inputs,
    float* __restrict__ h, f16* __restrict__ h16,
    const int* __restrict__ row_ptr, const float* __restrict__ msg,
    const float* __restrict__ wih, const float* __restrict__ whh,
    const float* __restrict__ bih, const float* __restrict__ bhh,
    const float* __restrict__ fw, const float* __restrict__ fb,
    float* __restrict__ out_t, int N)
{
    const int T = blockIdx.x * blockDim.x + threadIdx.x;
    const int n = T / LPN;
    const int sub = T & (LPN - 1);
    if (n >= N) return;

    float x[GIN];
#pragma unroll
    for (int k = 0; k < EF; ++k) x[k] = 0.0f;
    const int r0 = row_ptr[n], r1 = row_ptr[n + 1];
    for (int r = r0 + sub; r < r1; r += LPN) {
        const f32x4* mp = (const f32x4*)(msg + (size_t)r * MSTR);
        f32x4 a = mp[0], b = mp[1], c = mp[2];
        x[0] += a[0]; x[1] += a[1]; x[2] += a[2]; x[3] += a[3];
        x[4] += b[0]; x[5] += b[1]; x[6] += b[2]; x[7] += b[3];
        x[8] += c[0]; x[9] += c[1]; x[10] += c[2];
    }
    // butterfly reduce across the 8-lane group (stays within the wave)
#pragma unroll
    for (int off = 1; off < LPN; off <<= 1) {
#pragma unroll
        for (int k = 0; k < EF; ++k)
            x[k] += __shfl_xor(x[k], off);
    }
#pragma unroll
    for (int k = 0; k < NIN; ++k) x[EF + k] = node_inputs[(size_t)n * NIN + k];

    float hv[HF];
#pragma unroll
    for (int k = 0; k < HF; ++k) hv[k] = h[(size_t)n * HF + k];

    float hn[HF];
#pragma unroll
    for (int k = 0; k < HF; ++k) {
        float gir = bih[k];
        float giz = bih[HF + k];
        float gin = bih[2 * HF + k];
        float ghr = bhh[k];
        float ghz = bhh[HF + k];
        float ghn = bhh[2 * HF + k];
#pragma unroll
        for (int kk = 0; kk < GIN; ++kk) {
            gir = fmaf(x[kk], wih[(size_t)k * GIN + kk], gir);
            giz = fmaf(x[kk], wih[(size_t)(HF + k) * GIN + kk], giz);
            gin = fmaf(x[kk], wih[(size_t)(2 * HF + k) * GIN + kk], gin);
        }
#pragma unroll
        for (int kk = 0; kk < HF; ++kk) {
            ghr = fmaf(hv[kk], whh[(size_t)k * HF + kk], ghr);
            ghz = fmaf(hv[kk], whh[(size_t)(HF + k) * HF + kk], ghz);
            ghn = fmaf(hv[kk], whh[(size_t)(2 * HF + k) * HF + kk], ghn);
        }
        const float r2 = 1.0f / (1.0f + __expf(-(gir + ghr)));
        const float z  = 1.0f / (1.0f + __expf(-(giz + ghz)));
        const float nn = tanhf(gin + r2 * ghn);
        hn[k] = (1.0f - z) * nn + z * hv[k];
    }

    if (sub == 0) {
#pragma unroll
        for (int k = 0; k < HF; ++k) h[(size_t)n * HF + k] = hn[k];
        union { f16 hh[8]; uint4 q; } p4;
#pragma unroll
        for (int k = 0; k < 8; ++k) p4.hh[k] = (f16)hn[k];
        *(uint4*)(h16 + (size_t)n * 16) = p4.q;
        union { f16 hh[2]; uint32_t u; } p1;
        p1.hh[0] = (f16)hn[8]; p1.hh[1] = (f16)hn[9];
        *(uint32_t*)(h16 + (size_t)n * 16 + 8) = p1.u;

        float l0 = fb[0], l1 = fb[1];
#pragma unroll
        for (int k = 0; k < HF; ++k) {
            l0 = fmaf(hn[k], fw[k], l0);
            l1 = fmaf(hn[k], fw[HF + k], l1);
        }
        float2 lo = { l0, l1 };
        *(float2*)(out_t + (size_t)n * 2) = lo;
    }
}

extern "C" void kernel_launch(void* const* d_in, const int* in_sizes, int n_in,
                              void* d_out, int out_size, void* d_ws, size_t ws_size,
                              hipStream_t stream) {
    const float* node_inputs = (const float*)d_in[0];
    const float* edge_attr   = (const float*)d_in[1];
    const float* W1 = (const float*)d_in[2];
    const float* b1 = (const float*)d_in[3];
    const float* W2 = (const float*)d_in[4];
    const float* b2 = (const float*)d_in[5];
    const float* W3 = (const float*)d_in[6];
    const float* b3 = (const float*)d_in[7];
    const float* W4 = (const float*)d_in[8];
    const float* b4 = (const float*)d_in[9];
    const float* gru_wih = (const float*)d_in[10];
    const float* gru_whh = (const float*)d_in[11];
    const float* gru_bih = (const float*)d_in[12];
    const float* gru_bhh = (const float*)d_in[13];
    const float* fin_w   = (const float*)d_in[14];
    const float* fin_b   = (const float*)d_in[15];
    const int* src_ids = (const int*)d_in[16];
    const int* dst_ids = (const int*)d_in[17];

    const int N = in_sizes[0] / NIN;   // 20000
    const int E = in_sizes[1] / EF;    // 320000

    // ---- workspace carve-up (256B-aligned chunks) ----
    char* base = (char*)d_ws;
    size_t off = 0;
    auto alloc = [&](size_t bytes) -> char* {
        char* p = base + off;
        off += (bytes + 255) & ~(size_t)255;
        return p;
    };
    float* msg    = (float*)alloc((size_t)E * MSTR * 4);  // 15.4 MB
    f16*   eaB    = (f16*)  alloc((size_t)E * 8 * 2);
    f16*   eaA    = (f16*)  alloc((size_t)E * 4 * 2);
    // h16, hbuf, cnt kept CONTIGUOUS so one memset clears all three
    f16*   h16    = (f16*)  alloc((size_t)N * 16 * 2);
    float* hbuf   = (float*)alloc((size_t)N * HF * 4);
    int*   cnt    = (int*)  alloc((size_t)N * 4);
    f16*   wf     = (f16*)  alloc(52000 * 2);
    int*   row_ptr= (int*)  alloc((size_t)(N + 1) * 4);
    int*   nxt    = (int*)  alloc((size_t)N * 4);
    int2*  sd     = (int2*) alloc((size_t)E * 8);

    const int eb = (E + 255) / 256;
    const int nb = (N * LPN + 255) / 256;

    // ---- per-launch setup (d_ws is re-poisoned before every call) ----
    const size_t zspan = (size_t)((char*)cnt + (size_t)N * 4 - (char*)h16);
    hipMemsetAsync(h16, 0, zspan, stream);   // h16 + hbuf + cnt in one shot
    convert_and_count<<<eb, 256, 0, stream>>>(W1, W2, W3, W4, wf,
                                              dst_ids, cnt, E);
    scan_counts<<<1, 1024, 0, stream>>>(cnt, row_ptr, nxt, N, E);
    scatter_pack<<<eb, 256, 0, stream>>>(src_ids, dst_ids, edge_attr, nxt,
                                         sd, eaA, eaB, E);

    float* out = (float*)d_out;
    for (int t = 0; t < N_ITERS; ++t) {
        edge_mlp_mfma<<<eb, 256, 0, stream>>>(
            h16, wf, b1, b2, b3, b4, sd, eaA, eaB, msg, E);
        gru_node_kernel<<<nb, 256, 0, stream>>>(
            node_inputs, hbuf, h16, row_ptr, msg,
            gru_wih, gru_whh, gru_bih, gru_bhh,
            fin_w, fin_b, out + (size_t)t * N * 2, N);
    }
}